// Round 3
// baseline (552.630 us; speedup 1.0000x reference)
//
#include <hip/hip_runtime.h>

// Voxel pooling v4: scan (unchanged from v3) + two-phase acc.
// v3's acc was a serial dependent chain (shfl->load->atomic, 1-deep prefetch
// that the compiler collapsed to 20 VGPRs) at 1 block/CU: 424us, 8% VALUBusy.
// v4 acc: per round, waves COMPACT slice entries into an LDS queue (ballot +
// prefix sum), then PROCESS the queue with index-computed, fully independent
// steps: 3 entries/wave-step (20 lanes x float4 = one 320B ctx row each),
// 4-way unrolled -> 4+ L2 loads in flight per wave, no cross-iteration deps.

namespace {
constexpr int NVX = 128, NVY = 128, C = 80;
constexpr int B = 2, N = 6, D = 112, H = 16, W = 44;
constexpr int HW    = H * W;             // 704
constexpr int BN    = B * N;             // 12
constexpr int DHW   = D * HW;            // 78848
constexpr int NDHW  = N * DHW;           // 473088 (points per batch)
constexpr int TOTAL = B * NDHW;          // 946176
constexpr int NVOX  = B * NVY * NVX;     // 32768

constexpr int NBIN  = 256;               // bin = v & 255
constexpr int VPB   = NVOX / NBIN;       // 128 voxels per bin (vl = v>>8)
constexpr int SLOT  = 16;                // slice stride in int2 (128B)
constexpr int CAP   = 15;                // slots 0..14 data, slot15.x = count
constexpr int PTS_PER_BLK = 2048;
constexpr int SCAN_BLOCKS = TOTAL / PTS_PER_BLK;       // 462
constexpr int TR_BLOCKS   = BN * (C / 16) * (HW / 64); // 660
constexpr int PRE_BLOCKS  = SCAN_BLOCKS + TR_BLOCKS;   // 1122
constexpr int SPILLCAP = 65536;

// acc two-phase parameters
constexpr int ROUNDS = 4;
constexpr int SL_PER_ROUND = 116;        // 4*116 = 464 >= 462 slices
constexpr int QCAP  = 1792;              // >= 116*15 worst-case entries/round
constexpr int ACCS  = 81;                // acc stride: 81%32=17, bank-spread
}

// ---- 1. fused: LDS binning (blocks < SCAN_BLOCKS) | tiled transpose (rest) ----
__global__ __launch_bounds__(256) void pre_kernel(
    const int*   __restrict__ geom, const float* __restrict__ depth,
    const float* __restrict__ ctx,  float* __restrict__ ctx_t,
    int2* __restrict__ staging, int* __restrict__ spillcnt,
    int2* __restrict__ spill)
{
    __shared__ int2  stage[NBIN * SLOT];   // 32 KB
    __shared__ int   bcnt[NBIN];           // 1 KB
    __shared__ float tile[16 * 68];        // transpose scratch

    if (blockIdx.x < SCAN_BLOCKS) {
        const int t = threadIdx.x;
        bcnt[t] = 0;                       // NBIN == blockDim.x == 256
        __syncthreads();

        const int p0 = blockIdx.x * PTS_PER_BLK + t * 8;
        const int4* g4 = (const int4*)(geom + (size_t)3 * p0);  // 96B, aligned
        int4 q[6];
        #pragma unroll
        for (int i = 0; i < 6; ++i) q[i] = g4[i];
        const float4 d0 = *(const float4*)(depth + p0);
        const float4 d1 = *(const float4*)(depth + p0 + 4);
        const int xs[8] = {q[0].x, q[0].w, q[1].z, q[2].y,
                           q[3].x, q[3].w, q[4].z, q[5].y};
        const int ys[8] = {q[0].y, q[1].x, q[1].w, q[2].z,
                           q[3].y, q[4].x, q[4].w, q[5].z};
        const float ds[8] = {d0.x, d0.y, d0.z, d0.w, d1.x, d1.y, d1.z, d1.w};

        #pragma unroll
        for (int u = 0; u < 8; ++u) {
            const int x = xs[u], y = ys[u];
            if ((unsigned)x >= (unsigned)NVX || (unsigned)y >= (unsigned)NVY) continue;
            const int p   = p0 + u;
            const int b   = (p >= NDHW) ? 1 : 0;          // B == 2
            const int v   = (b * NVY + y) * NVX + x;
            const int bn  = (unsigned)p / (unsigned)DHW;
            const int hw  = (unsigned)p % (unsigned)HW;
            const int key = (v << 14) | (bn * HW + hw);   // v:15b | row:14b
            const int bin = v & 255;                      // uniform per block
            const int idx = atomicAdd(&bcnt[bin], 1);     // LDS atomic
            if (idx < CAP) {
                stage[bin * SLOT + idx] = make_int2(key, __float_as_int(ds[u]));
            } else {
                int s = atomicAdd(spillcnt, 1);
                if (s < SPILLCAP) spill[s] = make_int2(key, __float_as_int(ds[u]));
            }
        }
        __syncthreads();
        stage[t * SLOT + CAP].x = bcnt[t];   // embed count in slot 15
        __syncthreads();

        // stream out: 2048 int4, every global write a full 64B line
        const int4* src = (const int4*)stage;
        int4* dst = (int4*)staging;
        #pragma unroll
        for (int k = 0; k < 8; ++k) {
            const int i = k * 256 + t;            // 0..2047
            const int bin = i >> 3, part = i & 7; // 8 int4 per slice
            dst[((size_t)bin * SCAN_BLOCKS + blockIdx.x) * 8 + part] = src[i];
        }
    } else {
        // transpose ctx (bn, c, hw) -> ctx_t (bn*HW + hw, c), 16c x 64hw tiles
        const int tb  = blockIdx.x - SCAN_BLOCKS;
        const int bn  = tb / 55;
        const int rem = tb % 55;
        const int c0  = (rem / 11) * 16;
        const int hw0 = (rem % 11) * 64;
        const int t = threadIdx.x;
        const int cl = t >> 6, hwl = t & 63;
        #pragma unroll
        for (int r = 0; r < 4; ++r) {
            const int c = r * 4 + cl;
            tile[c * 68 + hwl] =
                ctx[(size_t)(bn * C + c0 + c) * HW + hw0 + hwl];
        }
        __syncthreads();
        const int cr = t & 15, hwr = t >> 4;
        #pragma unroll
        for (int r = 0; r < 4; ++r) {
            const int hw = r * 16 + hwr;
            ctx_t[(size_t)(bn * HW + hw0 + hw) * C + c0 + cr] =
                tile[cr * 68 + hw];
        }
    }
}

// ---- 2. two-phase acc: compact slices into LDS queue, then process ----
__global__ __launch_bounds__(1024) void acc_kernel(
    const int2* __restrict__ staging, const float* __restrict__ ctx_t,
    float* __restrict__ out)
{
    __shared__ float acc[VPB * ACCS];    // 41472 B
    __shared__ int2  queue[QCAP];        // 14336 B
    __shared__ int   qtail[ROUNDS];      // 16 B   (total 55824 <= 64KB)

    const int bin  = blockIdx.x;
    const int t    = threadIdx.x;
    const int wave = t >> 6, lane = t & 63;

    for (int i = t; i < VPB * ACCS; i += 1024) acc[i] = 0.f;
    if (t < ROUNDS) qtail[t] = 0;
    __syncthreads();

    const int g   = lane / 20;           // 0..2 = entry group, 3 = idle lanes
    const int l20 = lane - g * 20;
    const int ch0 = l20 * 4;             // this lane's 4-channel chunk

    for (int r = 0; r < ROUNDS; ++r) {
        // ---- fill: compact up to 116 slices' entries into queue ----
        const int s0 = r * SL_PER_ROUND;
        const int sub = lane >> 4, slot = lane & 15;
        for (int c = wave; c < (SL_PER_ROUND + 3) / 4; c += 16) {
            const int s = s0 + c * 4 + sub;           // 4 slices per wave-chunk
            int2 e = make_int2(0, 0);
            if (s < SCAN_BLOCKS)
                e = staging[((size_t)bin * SCAN_BLOCKS + s) * SLOT + slot];
            int cnt = __shfl(e.x, lane | 15);         // slot15.x = count
            cnt = cnt < CAP ? cnt : CAP;
            const bool valid = (s < SCAN_BLOCKS) && (slot < cnt);
            const unsigned long long mask = __ballot(valid);
            int base = 0;
            if (lane == 0) base = atomicAdd(&qtail[r], (int)__popcll(mask));
            base = __shfl(base, 0);
            if (valid) {
                const int prefix = (int)__popcll(mask & ((1ull << lane) - 1ull));
                queue[base + prefix] = e;
            }
        }
        __syncthreads();

        // ---- process: independent steps, 3 entries per wave-step, x4 unroll ----
        const int qn = qtail[r];
        const int ntrip = (qn + 2) / 3;
        for (int tb = wave; tb < ntrip; tb += 64) {
            #pragma unroll
            for (int k = 0; k < 4; ++k) {
                const int idx = (tb + k * 16) * 3 + g;
                const bool ok = (g < 3) && (idx < qn);
                const int2 kd = queue[ok ? idx : 0];  // same-addr broadcast/group
                const float dep = ok ? __int_as_float(kd.y) : 0.f;
                const int key = ok ? kd.x : 0;
                const int row = key & 16383;
                const int vl  = key >> 22;            // v>>8 (key = v<<14|row)
                const float4 cf = *(const float4*)(ctx_t + (size_t)row * C + ch0);
                const int ab = vl * ACCS + ch0;
                atomicAdd(&acc[ab + 0], dep * cf.x);
                atomicAdd(&acc[ab + 1], dep * cf.y);
                atomicAdd(&acc[ab + 2], dep * cf.z);
                atomicAdd(&acc[ab + 3], dep * cf.w);
            }
        }
        __syncthreads();
    }

    // ---- writeout: v = (vl<<8)|bin, contiguous 320B per voxel ----
    for (int i = t; i < VPB * C; i += 1024) {
        const int vl = i / C, ch = i - vl * C;
        out[(size_t)((vl << 8) | bin) * C + ch] = acc[vl * ACCS + ch];
    }
}

// ---- 3. spill fixup (exact, ~1.4k entries expected) ----
__global__ __launch_bounds__(256) void spill_kernel(
    const int* __restrict__ spillcnt, const int2* __restrict__ spill,
    const float* __restrict__ ctx_t, float* __restrict__ out)
{
    const int nwaves = gridDim.x * 4;
    const int wave   = blockIdx.x * 4 + (threadIdx.x >> 6);
    const int lane   = threadIdx.x & 63;
    int cnt = *spillcnt;
    if (cnt > SPILLCAP) cnt = SPILLCAP;
    for (int i = wave; i < cnt; i += nwaves) {
        const int2 e = spill[i];
        const int v   = e.x >> 14;          // key < 2^29, positive
        const int row = e.x & 16383;
        const float dep = __int_as_float(e.y);
        const float* c = ctx_t + (size_t)row * C;
        float* o = out + (size_t)v * C;
        unsafeAtomicAdd(o + lane, dep * c[lane]);
        if (lane < C - 64) unsafeAtomicAdd(o + 64 + lane, dep * c[64 + lane]);
    }
}

extern "C" void kernel_launch(void* const* d_in, const int* in_sizes, int n_in,
                              void* d_out, int out_size, void* d_ws, size_t ws_size,
                              hipStream_t stream) {
    const int*   geom  = (const int*)d_in[0];
    const float* depth = (const float*)d_in[1];
    const float* ctx   = (const float*)d_in[2];
    float*       out   = (float*)d_out;

    // Workspace (~18.4 MB, all segments 256B-multiple):
    char* ws = (char*)d_ws;
    int2* staging  = (int2*)ws; ws += (size_t)SCAN_BLOCKS * NBIN * SLOT * 8; // 15,138,816
    int2* spill    = (int2*)ws; ws += (size_t)SPILLCAP * 8;                  // 524,288
    int*  spillcnt = (int*)ws;  ws += 256;
    float* ctx_t   = (float*)ws;                                             // 2,703,360

    hipMemsetAsync(spillcnt, 0, 256, stream);

    pre_kernel  <<<dim3(PRE_BLOCKS), dim3(256),  0, stream>>>(
                    geom, depth, ctx, ctx_t, staging, spillcnt, spill);
    acc_kernel  <<<dim3(NBIN),       dim3(1024), 0, stream>>>(staging, ctx_t, out);
    spill_kernel<<<dim3(64),         dim3(256),  0, stream>>>(spillcnt, spill, ctx_t, out);
}

// Round 4
// 133.477 us; speedup vs baseline: 4.1403x; 4.1403x over previous
//
#include <hip/hip_runtime.h>

// Voxel pooling v5: scan (unchanged) + bucket-then-register-accumulate acc.
// v3/v4 post-mortem: both accs did 80 LDS f32 atomic lane-RMWs per point and
// both ran ~3.5 cy/lane-RMW (424/454us) -> the LDS atomic pipe (~1 lane/3.5cy,
// shared by all waves in the block) was the bottleneck, not load latency.
// v5 acc: phase 1 buckets entries into per-voxel LDS lists (ONE u32 counter
// RMW + one ds_write_b64 per entry = 20x less atomic work); phase 2 gives each
// wave 8 voxels, accumulating in REGISTERS (4 independent partial-sum chains,
// 8 L2 loads in flight), direct coalesced 320B store per voxel. No f32 atomics.

namespace {
constexpr int NVX = 128, NVY = 128, C = 80;
constexpr int B = 2, N = 6, D = 112, H = 16, W = 44;
constexpr int HW    = H * W;             // 704
constexpr int BN    = B * N;             // 12
constexpr int DHW   = D * HW;            // 78848
constexpr int NDHW  = N * DHW;           // 473088 (points per batch)
constexpr int TOTAL = B * NDHW;          // 946176
constexpr int NVOX  = B * NVY * NVX;     // 32768

constexpr int NBIN  = 256;               // bin = v & 255
constexpr int VPB   = NVOX / NBIN;       // 128 voxels per bin (vl = v>>8)
constexpr int SLOT  = 16;                // slice stride in int2 (128B)
constexpr int CAP   = 15;                // slots 0..14 data, slot15.x = count
constexpr int PTS_PER_BLK = 2048;
constexpr int SCAN_BLOCKS = TOTAL / PTS_PER_BLK;       // 462
constexpr int TR_BLOCKS   = BN * (C / 16) * (HW / 64); // 660
constexpr int PRE_BLOCKS  = SCAN_BLOCKS + TR_BLOCKS;   // 1122
constexpr int SPILLCAP = 65536;

constexpr int VCAP = 56;                 // per-voxel LDS list cap (lambda=28.9,
                                         // P(Poisson>56)~1e-5 -> <1 spill/run)
}

// ---- 1. fused: LDS binning (blocks < SCAN_BLOCKS) | tiled transpose (rest) ----
__global__ __launch_bounds__(256) void pre_kernel(
    const int*   __restrict__ geom, const float* __restrict__ depth,
    const float* __restrict__ ctx,  float* __restrict__ ctx_t,
    int2* __restrict__ staging, int* __restrict__ spillcnt,
    int2* __restrict__ spill)
{
    __shared__ int2  stage[NBIN * SLOT];   // 32 KB
    __shared__ int   bcnt[NBIN];           // 1 KB
    __shared__ float tile[16 * 68];        // transpose scratch

    if (blockIdx.x < SCAN_BLOCKS) {
        const int t = threadIdx.x;
        bcnt[t] = 0;                       // NBIN == blockDim.x == 256
        __syncthreads();

        const int p0 = blockIdx.x * PTS_PER_BLK + t * 8;
        const int4* g4 = (const int4*)(geom + (size_t)3 * p0);  // 96B, aligned
        int4 q[6];
        #pragma unroll
        for (int i = 0; i < 6; ++i) q[i] = g4[i];
        const float4 d0 = *(const float4*)(depth + p0);
        const float4 d1 = *(const float4*)(depth + p0 + 4);
        const int xs[8] = {q[0].x, q[0].w, q[1].z, q[2].y,
                           q[3].x, q[3].w, q[4].z, q[5].y};
        const int ys[8] = {q[0].y, q[1].x, q[1].w, q[2].z,
                           q[3].y, q[4].x, q[4].w, q[5].z};
        const float ds[8] = {d0.x, d0.y, d0.z, d0.w, d1.x, d1.y, d1.z, d1.w};

        #pragma unroll
        for (int u = 0; u < 8; ++u) {
            const int x = xs[u], y = ys[u];
            if ((unsigned)x >= (unsigned)NVX || (unsigned)y >= (unsigned)NVY) continue;
            const int p   = p0 + u;
            const int b   = (p >= NDHW) ? 1 : 0;          // B == 2
            const int v   = (b * NVY + y) * NVX + x;
            const int bn  = (unsigned)p / (unsigned)DHW;
            const int hw  = (unsigned)p % (unsigned)HW;
            const int key = (v << 14) | (bn * HW + hw);   // v:15b | row:14b
            const int bin = v & 255;                      // uniform per block
            const int idx = atomicAdd(&bcnt[bin], 1);     // LDS atomic
            if (idx < CAP) {
                stage[bin * SLOT + idx] = make_int2(key, __float_as_int(ds[u]));
            } else {
                int s = atomicAdd(spillcnt, 1);
                if (s < SPILLCAP) spill[s] = make_int2(key, __float_as_int(ds[u]));
            }
        }
        __syncthreads();
        stage[t * SLOT + CAP].x = bcnt[t];   // embed count in slot 15
        __syncthreads();

        // stream out: 2048 int4, every global write a full 64B line
        const int4* src = (const int4*)stage;
        int4* dst = (int4*)staging;
        #pragma unroll
        for (int k = 0; k < 8; ++k) {
            const int i = k * 256 + t;            // 0..2047
            const int bin = i >> 3, part = i & 7; // 8 int4 per slice
            dst[((size_t)bin * SCAN_BLOCKS + blockIdx.x) * 8 + part] = src[i];
        }
    } else {
        // transpose ctx (bn, c, hw) -> ctx_t (bn*HW + hw, c), 16c x 64hw tiles
        const int tb  = blockIdx.x - SCAN_BLOCKS;
        const int bn  = tb / 55;
        const int rem = tb % 55;
        const int c0  = (rem / 11) * 16;
        const int hw0 = (rem % 11) * 64;
        const int t = threadIdx.x;
        const int cl = t >> 6, hwl = t & 63;
        #pragma unroll
        for (int r = 0; r < 4; ++r) {
            const int c = r * 4 + cl;
            tile[c * 68 + hwl] =
                ctx[(size_t)(bn * C + c0 + c) * HW + hw0 + hwl];
        }
        __syncthreads();
        const int cr = t & 15, hwr = t >> 4;
        #pragma unroll
        for (int r = 0; r < 4; ++r) {
            const int hw = r * 16 + hwr;
            ctx_t[(size_t)(bn * HW + hw0 + hw) * C + c0 + cr] =
                tile[cr * 68 + hw];
        }
    }
}

// ---- 2. acc: bucket into per-voxel LDS lists, then register-accumulate ----
__global__ __launch_bounds__(1024) void acc_kernel(
    const int2* __restrict__ staging, const float* __restrict__ ctx_t,
    float* __restrict__ out, int* __restrict__ spillcnt,
    int2* __restrict__ spill)
{
    __shared__ int2 list[VPB * VCAP];   // 57344 B
    __shared__ int  vcnt[VPB];          //   512 B

    const int bin  = blockIdx.x;
    const int t    = threadIdx.x;
    const int wave = t >> 6, lane = t & 63;

    if (t < VPB) vcnt[t] = 0;
    __syncthreads();

    // ---- phase 1: bucket. 4 slices per 64-lane chunk, coalesced 512B reads.
    const int sub = lane >> 4, slot = lane & 15;
    for (int c = wave; c < (SCAN_BLOCKS + 3) / 4; c += 16) {
        const int s = c * 4 + sub;
        int2 e = make_int2(0, 0);
        if (s < SCAN_BLOCKS)
            e = staging[((size_t)bin * SCAN_BLOCKS + s) * SLOT + slot];
        int cnt = __shfl(e.x, lane | 15);     // slot15.x = count
        cnt = cnt < CAP ? cnt : CAP;
        if (s < SCAN_BLOCKS && slot < cnt) {
            const int vl  = e.x >> 22;        // key = v<<14|row, v>>8 = vl
            const int idx = atomicAdd(&vcnt[vl], 1);   // ONE u32 RMW per entry
            if (idx < VCAP) {
                list[vl * VCAP + idx] = e;
            } else {
                int sp = atomicAdd(spillcnt, 1);
                if (sp < SPILLCAP) spill[sp] = e;
            }
        }
    }
    __syncthreads();

    // ---- phase 2: one wave per voxel, register accumulation, no atomics.
    const int off2 = 64 + (lane & 15);        // channels 64..79 (dup for lane>=16)
    for (int vv = 0; vv < VPB / 16; ++vv) {   // 8 voxels per wave
        const int vl = wave * (VPB / 16) + vv;
        int n = vcnt[vl];
        n = n < VCAP ? n : VCAP;
        const int2* lp = list + vl * VCAP;

        float a0 = 0.f, a1 = 0.f, a2 = 0.f, a3 = 0.f;
        float b0 = 0.f, b1 = 0.f, b2 = 0.f, b3 = 0.f;
        int j = 0;
        for (; j + 4 <= n; j += 4) {          // 4 independent chains, 8 loads in flight
            const int2 e0 = lp[j], e1 = lp[j + 1], e2 = lp[j + 2], e3 = lp[j + 3];
            const float* c0 = ctx_t + (size_t)(e0.x & 16383) * C;
            const float* c1 = ctx_t + (size_t)(e1.x & 16383) * C;
            const float* c2 = ctx_t + (size_t)(e2.x & 16383) * C;
            const float* c3 = ctx_t + (size_t)(e3.x & 16383) * C;
            const float f0 = c0[lane], f1 = c1[lane], f2 = c2[lane], f3 = c3[lane];
            const float g0 = c0[off2], g1 = c1[off2], g2 = c2[off2], g3 = c3[off2];
            const float d0 = __int_as_float(e0.y), d1 = __int_as_float(e1.y);
            const float d2 = __int_as_float(e2.y), d3 = __int_as_float(e3.y);
            a0 += d0 * f0; a1 += d1 * f1; a2 += d2 * f2; a3 += d3 * f3;
            b0 += d0 * g0; b1 += d1 * g1; b2 += d2 * g2; b3 += d3 * g3;
        }
        for (; j < n; ++j) {
            const int2 e = lp[j];
            const float* c = ctx_t + (size_t)(e.x & 16383) * C;
            const float d = __int_as_float(e.y);
            a0 += d * c[lane];
            b0 += d * c[off2];
        }
        const float av = (a0 + a1) + (a2 + a3);
        const float bv = (b0 + b1) + (b2 + b3);
        float* o = out + (size_t)((vl << 8) | bin) * C;   // v = vl<<8 | bin
        o[lane] = av;
        if (lane < 16) o[64 + lane] = bv;
    }
}

// ---- 3. spill fixup (exact; ~1.2k entries from scan + <1 from acc) ----
__global__ __launch_bounds__(256) void spill_kernel(
    const int* __restrict__ spillcnt, const int2* __restrict__ spill,
    const float* __restrict__ ctx_t, float* __restrict__ out)
{
    const int nwaves = gridDim.x * 4;
    const int wave   = blockIdx.x * 4 + (threadIdx.x >> 6);
    const int lane   = threadIdx.x & 63;
    int cnt = *spillcnt;
    if (cnt > SPILLCAP) cnt = SPILLCAP;
    for (int i = wave; i < cnt; i += nwaves) {
        const int2 e = spill[i];
        const int v   = e.x >> 14;          // key < 2^29, positive
        const int row = e.x & 16383;
        const float dep = __int_as_float(e.y);
        const float* c = ctx_t + (size_t)row * C;
        float* o = out + (size_t)v * C;
        unsafeAtomicAdd(o + lane, dep * c[lane]);
        if (lane < C - 64) unsafeAtomicAdd(o + 64 + lane, dep * c[64 + lane]);
    }
}

extern "C" void kernel_launch(void* const* d_in, const int* in_sizes, int n_in,
                              void* d_out, int out_size, void* d_ws, size_t ws_size,
                              hipStream_t stream) {
    const int*   geom  = (const int*)d_in[0];
    const float* depth = (const float*)d_in[1];
    const float* ctx   = (const float*)d_in[2];
    float*       out   = (float*)d_out;

    // Workspace (~18.4 MB, all segments 256B-multiple):
    char* ws = (char*)d_ws;
    int2* staging  = (int2*)ws; ws += (size_t)SCAN_BLOCKS * NBIN * SLOT * 8; // 15,138,816
    int2* spill    = (int2*)ws; ws += (size_t)SPILLCAP * 8;                  // 524,288
    int*  spillcnt = (int*)ws;  ws += 256;
    float* ctx_t   = (float*)ws;                                             // 2,703,360

    hipMemsetAsync(spillcnt, 0, 256, stream);

    pre_kernel  <<<dim3(PRE_BLOCKS), dim3(256),  0, stream>>>(
                    geom, depth, ctx, ctx_t, staging, spillcnt, spill);
    acc_kernel  <<<dim3(NBIN),       dim3(1024), 0, stream>>>(
                    staging, ctx_t, out, spillcnt, spill);
    spill_kernel<<<dim3(64),         dim3(256),  0, stream>>>(spillcnt, spill, ctx_t, out);
}